// Round 1
// baseline (221.690 us; speedup 1.0000x reference)
//
#include <hip/hip_runtime.h>

typedef __attribute__((ext_vector_type(8))) short bf16x8;
typedef __attribute__((ext_vector_type(4))) float f32x4;

#define HIDDEN 2880
#define QKV_DIM 5120
#define NH 64
#define NKV 8
#define HD 64
#define ATT_DIM 4096
#define WINDOW 128
#define SM_SCALE 0.125f

__device__ __forceinline__ ushort f2bf(float f) {
  union { float f; unsigned u; } a; a.f = f;
  unsigned r = a.u + 0x7fffu + ((a.u >> 16) & 1u);
  return (ushort)(r >> 16);
}

__device__ __forceinline__ void gload_lds16(const void* g, void* l) {
  __builtin_amdgcn_global_load_lds((const __attribute__((address_space(1))) void*)g,
                                   (__attribute__((address_space(3))) void*)l, 16, 0, 0);
}

// ---------------- f32 -> bf16 convert ----------------
__global__ __launch_bounds__(256) void cvt_f32_bf16(const float* __restrict__ in,
                                                    ushort* __restrict__ out, int n4) {
  int i = blockIdx.x * blockDim.x + threadIdx.x;
  int stride = gridDim.x * blockDim.x;
  for (; i < n4; i += stride) {
    float4 v = ((const float4*)in)[i];
    ushort4 o = { f2bf(v.x), f2bf(v.y), f2bf(v.z), f2bf(v.w) };
    ((ushort4*)out)[i] = o;
  }
}

// ---------------- RMSNorm -> bf16 ----------------
__global__ __launch_bounds__(256) void rmsnorm_bf16(const float* __restrict__ x,
                                                    const float* __restrict__ scale,
                                                    ushort* __restrict__ t) {
  int row = blockIdx.x;
  int tid = threadIdx.x;
  const float4* xr = (const float4*)(x + (size_t)row * HIDDEN);
  // 720 float4 per row: indices tid, tid+256, tid+512(<720 iff tid<208)
  float4 a0 = xr[tid];
  float4 a1 = xr[tid + 256];
  bool has2 = tid < 208;
  float4 a2 = has2 ? xr[tid + 512] : float4{0.f, 0.f, 0.f, 0.f};
  float ss = a0.x*a0.x + a0.y*a0.y + a0.z*a0.z + a0.w*a0.w
           + a1.x*a1.x + a1.y*a1.y + a1.z*a1.z + a1.w*a1.w
           + a2.x*a2.x + a2.y*a2.y + a2.z*a2.z + a2.w*a2.w;
  for (int m = 1; m < 64; m <<= 1) ss += __shfl_xor(ss, m, 64);
  __shared__ float red[4];
  if ((tid & 63) == 0) red[tid >> 6] = ss;
  __syncthreads();
  ss = red[0] + red[1] + red[2] + red[3];
  float r = rsqrtf(ss / (float)HIDDEN + 1e-5f);
  ushort4* tr = (ushort4*)(t + (size_t)row * HIDDEN);
  const float4* sc4 = (const float4*)scale;
  {
    float4 s = sc4[tid];
    ushort4 o = { f2bf(a0.x*r*s.x), f2bf(a0.y*r*s.y), f2bf(a0.z*r*s.z), f2bf(a0.w*r*s.w) };
    tr[tid] = o;
  }
  {
    float4 s = sc4[tid + 256];
    ushort4 o = { f2bf(a1.x*r*s.x), f2bf(a1.y*r*s.y), f2bf(a1.z*r*s.z), f2bf(a1.w*r*s.w) };
    tr[tid + 256] = o;
  }
  if (has2) {
    float4 s = sc4[tid + 512];
    ushort4 o = { f2bf(a2.x*r*s.x), f2bf(a2.y*r*s.y), f2bf(a2.z*r*s.z), f2bf(a2.w*r*s.w) };
    tr[tid + 512] = o;
  }
}

// ---------------- bf16 GEMM: C[M,N] = A[M,K] * B[N,K]^T + bias (+resid) ----------------
// 128x128 tile, BK=64, 4 waves (2x2), each wave 64x64 = 4x4 frags of 16x16x32.
// LDS staged via global_load_lds w/ pre-swizzled global source; reads XOR-swizzled.
template <int EPI>
__global__ __launch_bounds__(256)
void gemm_bf16_nt(const ushort* __restrict__ A, const ushort* __restrict__ B,
                  const float* __restrict__ bias, const float* __restrict__ resid,
                  float* __restrict__ C, int M, int N, int K) {
  __shared__ __align__(16) ushort Al[128 * 64];
  __shared__ __align__(16) ushort Bl[128 * 64];
  int tid = threadIdx.x;
  int wave = tid >> 6, lane = tid & 63;
  int row0 = blockIdx.x * 128, col0 = blockIdx.y * 128;
  int srow = wave * 32 + (lane >> 3);      // staging row (q adds 8 each)
  int schunk = (lane & 7) ^ (lane >> 3);   // swizzled 16B chunk in 128B row
  const ushort* Ab = A + (size_t)(row0 + srow) * K + schunk * 8;
  int wr = (wave >> 1) * 64, wc = (wave & 1) * 64;
  f32x4 acc[4][4] = {};

  for (int k0 = 0; k0 < K; k0 += 64) {
#pragma unroll
    for (int q = 0; q < 4; ++q) {
      gload_lds16(Ab + (size_t)(q * 8) * K + k0, Al + (wave * 4 + q) * 512);
      int br = col0 + srow + q * 8;
      if (br > N - 1) br = N - 1;
      gload_lds16(B + (size_t)br * K + k0 + schunk * 8, Bl + (wave * 4 + q) * 512);
    }
    __syncthreads();
#pragma unroll
    for (int ks = 0; ks < 2; ++ks) {
      bf16x8 af[4];
#pragma unroll
      for (int mt = 0; mt < 4; ++mt) {
        int r = wr + mt * 16 + (lane & 15);
        int off = (r * 128 + (ks * 32 + ((lane >> 4) << 3)) * 2) ^ ((r & 7) << 4);
        af[mt] = *(const bf16x8*)((const char*)Al + off);
      }
#pragma unroll
      for (int nt = 0; nt < 4; ++nt) {
        int r = wc + nt * 16 + (lane & 15);
        int off = (r * 128 + (ks * 32 + ((lane >> 4) << 3)) * 2) ^ ((r & 7) << 4);
        bf16x8 bfr = *(const bf16x8*)((const char*)Bl + off);
#pragma unroll
        for (int mt = 0; mt < 4; ++mt)
          acc[mt][nt] = __builtin_amdgcn_mfma_f32_16x16x32_bf16(af[mt], bfr, acc[mt][nt], 0, 0, 0);
      }
    }
    __syncthreads();
  }
  // epilogue: C/D layout col=lane&15, row=(lane>>4)*4+r  (m89-verified)
#pragma unroll
  for (int mt = 0; mt < 4; ++mt) {
#pragma unroll
    for (int nt = 0; nt < 4; ++nt) {
#pragma unroll
      for (int r = 0; r < 4; ++r) {
        int row = row0 + wr + mt * 16 + ((lane >> 4) << 2) + r;
        int col = col0 + wc + nt * 16 + (lane & 15);
        if (col < N) {
          float v = acc[mt][nt][r] + bias[col];
          if (EPI == 1) v += resid[(size_t)row * N + col];
          C[(size_t)row * N + col] = v;
        }
      }
    }
  }
}

// ---------------- RoPE + split + bf16 cast ----------------
__global__ __launch_bounds__(256)
void rope_split(const float* __restrict__ qkv, ushort* __restrict__ qb,
                ushort* __restrict__ kb, ushort* __restrict__ vb) {
  int tok = blockIdx.x;
  int tid = threadIdx.x;
  __shared__ float cs[32], sn[32];
  if (tid < 32) {
    float d = (float)tid;
    float freq = powf(150000.0f, d / 32.0f);
    float conc = 0.1f * logf(32.0f) + 1.0f;
    float lg = logf(150000.0f);
    float low = 32.0f * logf(4096.0f / (32.0f * 6.2831853f)) / lg;
    float high = 32.0f * logf(4096.0f / 6.2831853f) / lg;
    float ramp = (d - low) / (high - low);
    float cl = fminf(fmaxf(ramp, 0.0f), 1.0f);
    float mask = 1.0f - cl;
    float inv_freq = (1.0f - mask) / (32.0f * freq) + mask / freq;
    float fr = (float)tok * inv_freq;
    cs[tid] = cosf(fr) * conc;
    sn[tid] = sinf(fr) * conc;
  }
  __syncthreads();
  const float* row = qkv + (size_t)tok * QKV_DIM;
  // q: 64 heads * 32 pairs = 2048 pairs
#pragma unroll
  for (int it = 0; it < 8; ++it) {
    int p = tid + it * 256;
    int hd = p >> 5, d = p & 31;
    float x1 = row[hd * 64 + d], x2 = row[hd * 64 + d + 32];
    float c = cs[d], s = sn[d];
    size_t o = ((size_t)tok * NH + hd) * HD + d;
    qb[o] = f2bf(x1 * c - x2 * s);
    qb[o + 32] = f2bf(x2 * c + x1 * s);
  }
  // k: 8 heads * 32 pairs = 256 pairs
  {
    int p = tid;
    int hd = p >> 5, d = p & 31;
    float x1 = row[4096 + hd * 64 + d], x2 = row[4096 + hd * 64 + d + 32];
    float c = cs[d], s = sn[d];
    size_t o = ((size_t)tok * NKV + hd) * HD + d;
    kb[o] = f2bf(x1 * c - x2 * s);
    kb[o + 32] = f2bf(x2 * c + x1 * s);
  }
  // v: 512 elements
#pragma unroll
  for (int it = 0; it < 2; ++it) {
    int p = tid + it * 256;
    vb[(size_t)tok * (NKV * HD) + p] = f2bf(row[4608 + p]);
  }
}

// ---------------- attention: sliding window 128 + sink ----------------
// grid = (n/32, NKV). 512 threads = 8 waves, wave w handles head kv*8+w over 32 queries.
// Keys [qstart-128, qstart+32) = 160 rows staged in LDS (K swizzled, V transposed).
__global__ __launch_bounds__(512)
void attn_fused(const ushort* __restrict__ qb, const ushort* __restrict__ kb,
                const ushort* __restrict__ vb, const float* __restrict__ sinks,
                ushort* __restrict__ attn, int n) {
  __shared__ __align__(16) ushort Kl[160 * 64];   // [key][dim], XOR-swizzled rows of 128B
  __shared__ __align__(16) ushort Vt[64 * 168];   // [dim][key], padded stride
  __shared__ __align__(16) ushort Pl[8][32 * 40]; // per-wave P chunk [32 q][40 keys-pad]
  int tid = threadIdx.x;
  int wave = tid >> 6, lane = tid & 63;
  int qstart = blockIdx.x * 32;
  int kv = blockIdx.y;
  int head = kv * 8 + wave;
  int key0 = qstart - 128;

  // stage K via global_load_lds (pre-swizzled global source, linear LDS)
  for (int i = 0; i < 3; ++i) {
    int rowb = i * 64 + wave * 8;
    if (rowb < 160) {
      int r = rowb + (lane >> 3);
      int gj = key0 + r; if (gj < 0) gj = 0;
      int chunk = (lane & 7) ^ (lane >> 3);
      gload_lds16(kb + ((size_t)gj * NKV + kv) * HD + chunk * 8, Kl + rowb * 64);
    }
  }
  // stage V transposed
  for (int e = tid; e < 160 * 16; e += 512) {
    int j = e >> 4, d4 = (e & 15) << 2;
    int gj = key0 + j; if (gj < 0) gj = 0;
    ushort4 v = *(const ushort4*)(vb + ((size_t)gj * NKV + kv) * HD + d4);
    Vt[(d4 + 0) * 168 + j] = v.x;
    Vt[(d4 + 1) * 168 + j] = v.y;
    Vt[(d4 + 2) * 168 + j] = v.z;
    Vt[(d4 + 3) * 168 + j] = v.w;
  }
  // Q fragments straight from global
  bf16x8 qf[2][2];
#pragma unroll
  for (int mt = 0; mt < 2; ++mt)
#pragma unroll
    for (int ks = 0; ks < 2; ++ks) {
      int r = qstart + mt * 16 + (lane & 15);
      int kk = ks * 32 + ((lane >> 4) << 3);
      qf[mt][ks] = *(const bf16x8*)(qb + ((size_t)r * NH + head) * HD + kk);
    }
  __syncthreads();

  // S = Q K^T  (32 x 160)
  f32x4 s[2][10] = {};
#pragma unroll
  for (int nt = 0; nt < 10; ++nt) {
#pragma unroll
    for (int ks = 0; ks < 2; ++ks) {
      int r = nt * 16 + (lane & 15);
      int off = (r * 128 + (ks * 32 + ((lane >> 4) << 3)) * 2) ^ ((r & 7) << 4);
      bf16x8 kf = *(const bf16x8*)((const char*)Kl + off);
      s[0][nt] = __builtin_amdgcn_mfma_f32_16x16x32_bf16(qf[0][ks], kf, s[0][nt], 0, 0, 0);
      s[1][nt] = __builtin_amdgcn_mfma_f32_16x16x32_bf16(qf[1][ks], kf, s[1][nt], 0, 0, 0);
    }
  }

  // mask + scale + softmax (single pass; sink folded into max & denominator)
  float lrow[2][4];
  float snk = sinks[head];
#pragma unroll
  for (int mt = 0; mt < 2; ++mt) {
#pragma unroll
    for (int r = 0; r < 4; ++r) {
      int i = qstart + mt * 16 + ((lane >> 4) << 2) + r;
      float mx = -1e30f;
#pragma unroll
      for (int nt = 0; nt < 10; ++nt) {
        int j = key0 + nt * 16 + (lane & 15);
        bool ok = (j >= 0) && (j <= i) && (j > i - WINDOW);
        float val = ok ? s[mt][nt][r] * SM_SCALE : -1e30f;
        s[mt][nt][r] = val;
        mx = fmaxf(mx, val);
      }
      mx = fmaxf(mx, __shfl_xor(mx, 1, 64));
      mx = fmaxf(mx, __shfl_xor(mx, 2, 64));
      mx = fmaxf(mx, __shfl_xor(mx, 4, 64));
      mx = fmaxf(mx, __shfl_xor(mx, 8, 64));
      mx = fmaxf(mx, snk);
      float sum = 0.f;
#pragma unroll
      for (int nt = 0; nt < 10; ++nt) {
        float p = expf(s[mt][nt][r] - mx);
        s[mt][nt][r] = p;
        sum += p;
      }
      sum += __shfl_xor(sum, 1, 64);
      sum += __shfl_xor(sum, 2, 64);
      sum += __shfl_xor(sum, 4, 64);
      sum += __shfl_xor(sum, 8, 64);
      sum += expf(snk - mx);
      lrow[mt][r] = sum;
    }
  }

  // PV in 5 chunks of 32 keys, P relayout through per-wave LDS
  f32x4 o[2][4] = {};
#pragma unroll
  for (int kc = 0; kc < 5; ++kc) {
    __syncthreads();
#pragma unroll
    for (int mt = 0; mt < 2; ++mt)
#pragma unroll
      for (int t2 = 0; t2 < 2; ++t2) {
        int nt = kc * 2 + t2;
#pragma unroll
        for (int r = 0; r < 4; ++r) {
          int prow = mt * 16 + ((lane >> 4) << 2) + r;
          int pcol = t2 * 16 + (lane & 15);
          Pl[wave][prow * 40 + pcol] = f2bf(s[mt][nt][r]);
        }
      }
    __syncthreads();
    bf16x8 pa[2];
#pragma unroll
    for (int mt = 0; mt < 2; ++mt) {
      int r = mt * 16 + (lane & 15);
      pa[mt] = *(const bf16x8*)(&Pl[wave][r * 40 + ((lane >> 4) << 3)]);
    }
#pragma unroll
    for (int nt = 0; nt < 4; ++nt) {
      int d = nt * 16 + (lane & 15);
      int kk = kc * 32 + ((lane >> 4) << 3);
      bf16x8 vf = *(const bf16x8*)(&Vt[d * 168 + kk]);
      o[0][nt] = __builtin_amdgcn_mfma_f32_16x16x32_bf16(pa[0], vf, o[0][nt], 0, 0, 0);
      o[1][nt] = __builtin_amdgcn_mfma_f32_16x16x32_bf16(pa[1], vf, o[1][nt], 0, 0, 0);
    }
  }

  // epilogue: divide by denominator, write bf16 [n][64 heads][64]
#pragma unroll
  for (int mt = 0; mt < 2; ++mt)
#pragma unroll
    for (int nt = 0; nt < 4; ++nt)
#pragma unroll
      for (int r = 0; r < 4; ++r) {
        int row = qstart + mt * 16 + ((lane >> 4) << 2) + r;
        int d = nt * 16 + (lane & 15);
        float val = o[mt][nt][r] / lrow[mt][r];
        attn[((size_t)row * NH + head) * HD + d] = f2bf(val);
      }
}

extern "C" void kernel_launch(void* const* d_in, const int* in_sizes, int n_in,
                              void* d_out, int out_size, void* d_ws, size_t ws_size,
                              hipStream_t stream) {
  const float* x      = (const float*)d_in[0];
  const float* nscale = (const float*)d_in[1];
  const float* qkv_w  = (const float*)d_in[2];
  const float* qkv_b  = (const float*)d_in[3];
  const float* out_w  = (const float*)d_in[4];
  const float* out_b  = (const float*)d_in[5];
  const float* sinks  = (const float*)d_in[6];
  float* out = (float*)d_out;
  int n = in_sizes[0] / HIDDEN;  // 1536

  char* ws = (char*)d_ws;
  size_t off = 0;
  auto alloc = [&](size_t bytes) {
    char* p = ws + off;
    off += (bytes + 255) & ~(size_t)255;
    return p;
  };
  ushort* t_bf    = (ushort*)alloc((size_t)n * HIDDEN * 2);
  ushort* qkvw_bf = (ushort*)alloc((size_t)QKV_DIM * HIDDEN * 2);
  ushort* outw_bf = (ushort*)alloc((size_t)HIDDEN * ATT_DIM * 2);
  float*  qkv     = (float*)alloc((size_t)n * QKV_DIM * 4);
  ushort* q_bf    = (ushort*)alloc((size_t)n * NH * HD * 2);
  ushort* k_bf    = (ushort*)alloc((size_t)n * NKV * HD * 2);
  ushort* v_bf    = (ushort*)alloc((size_t)n * NKV * HD * 2);
  ushort* attn    = (ushort*)alloc((size_t)n * ATT_DIM * 2);

  cvt_f32_bf16<<<2048, 256, 0, stream>>>(qkv_w, qkvw_bf, QKV_DIM * HIDDEN / 4);
  cvt_f32_bf16<<<2048, 256, 0, stream>>>(out_w, outw_bf, HIDDEN * ATT_DIM / 4);
  rmsnorm_bf16<<<n, 256, 0, stream>>>(x, nscale, t_bf);
  gemm_bf16_nt<0><<<dim3(n / 128, QKV_DIM / 128), 256, 0, stream>>>(
      t_bf, qkvw_bf, qkv_b, nullptr, qkv, n, QKV_DIM, HIDDEN);
  rope_split<<<n, 256, 0, stream>>>(qkv, q_bf, k_bf, v_bf);
  attn_fused<<<dim3(n / 32, NKV), 512, 0, stream>>>(q_bf, k_bf, v_bf, sinks, attn, n);
  gemm_bf16_nt<1><<<dim3(n / 128, (HIDDEN + 127) / 128), 256, 0, stream>>>(
      attn, outw_bf, out_b, x, out, n, HIDDEN, ATT_DIM);
}

// Round 2
// 213.800 us; speedup vs baseline: 1.0369x; 1.0369x over previous
//
#include <hip/hip_runtime.h>

typedef __attribute__((ext_vector_type(8))) short bf16x8;
typedef __attribute__((ext_vector_type(4))) float f32x4;

#define HIDDEN 2880
#define QKV_DIM 5120
#define NH 64
#define NKV 8
#define HD 64
#define ATT_DIM 4096
#define WINDOW 128
#define SM_SCALE 0.125f

__device__ __forceinline__ ushort f2bf(float f) {
  union { float f; unsigned u; } a; a.f = f;
  unsigned r = a.u + 0x7fffu + ((a.u >> 16) & 1u);
  return (ushort)(r >> 16);
}

__device__ __forceinline__ void gload_lds16(const void* g, void* l) {
  __builtin_amdgcn_global_load_lds((const __attribute__((address_space(1))) void*)g,
                                   (__attribute__((address_space(3))) void*)l, 16, 0, 0);
}

// ---------------- f32 -> bf16 convert ----------------
__global__ __launch_bounds__(256) void cvt_f32_bf16(const float* __restrict__ in,
                                                    ushort* __restrict__ out, int n4) {
  int i = blockIdx.x * blockDim.x + threadIdx.x;
  int stride = gridDim.x * blockDim.x;
  for (; i < n4; i += stride) {
    float4 v = ((const float4*)in)[i];
    ushort4 o = { f2bf(v.x), f2bf(v.y), f2bf(v.z), f2bf(v.w) };
    ((ushort4*)out)[i] = o;
  }
}

// ---------------- RMSNorm -> bf16 ----------------
__global__ __launch_bounds__(256) void rmsnorm_bf16(const float* __restrict__ x,
                                                    const float* __restrict__ scale,
                                                    ushort* __restrict__ t) {
  int row = blockIdx.x;
  int tid = threadIdx.x;
  const float4* xr = (const float4*)(x + (size_t)row * HIDDEN);
  float4 a0 = xr[tid];
  float4 a1 = xr[tid + 256];
  bool has2 = tid < 208;
  float4 a2 = has2 ? xr[tid + 512] : float4{0.f, 0.f, 0.f, 0.f};
  float ss = a0.x*a0.x + a0.y*a0.y + a0.z*a0.z + a0.w*a0.w
           + a1.x*a1.x + a1.y*a1.y + a1.z*a1.z + a1.w*a1.w
           + a2.x*a2.x + a2.y*a2.y + a2.z*a2.z + a2.w*a2.w;
  for (int m = 1; m < 64; m <<= 1) ss += __shfl_xor(ss, m, 64);
  __shared__ float red[4];
  if ((tid & 63) == 0) red[tid >> 6] = ss;
  __syncthreads();
  ss = red[0] + red[1] + red[2] + red[3];
  float r = rsqrtf(ss / (float)HIDDEN + 1e-5f);
  ushort4* tr = (ushort4*)(t + (size_t)row * HIDDEN);
  const float4* sc4 = (const float4*)scale;
  {
    float4 s = sc4[tid];
    ushort4 o = { f2bf(a0.x*r*s.x), f2bf(a0.y*r*s.y), f2bf(a0.z*r*s.z), f2bf(a0.w*r*s.w) };
    tr[tid] = o;
  }
  {
    float4 s = sc4[tid + 256];
    ushort4 o = { f2bf(a1.x*r*s.x), f2bf(a1.y*r*s.y), f2bf(a1.z*r*s.z), f2bf(a1.w*r*s.w) };
    tr[tid + 256] = o;
  }
  if (has2) {
    float4 s = sc4[tid + 512];
    ushort4 o = { f2bf(a2.x*r*s.x), f2bf(a2.y*r*s.y), f2bf(a2.z*r*s.z), f2bf(a2.w*r*s.w) };
    tr[tid + 512] = o;
  }
}

// ---------------- pipelined bf16 GEMM: C[M,N] = A[M,K] * B[N,K]^T + bias (+resid) ----------------
// BM=128, BN=64*NFRAG, BK=64, 8 waves (2 row x 4 col), per-wave 64 x 16*NFRAG.
// Triple-buffered LDS, 2 phases per K-tile, counted vmcnt (T3+T4), T2 swizzle, T5 setprio.
// Correctness depends ONLY on the tile-boundary vmcnt+barrier; per-phase barriers are perf.
template <int NFRAG, int EPI>
__global__ __launch_bounds__(512)
void gemm_pipe(const ushort* __restrict__ A, const ushort* __restrict__ B,
               const float* __restrict__ bias, const float* __restrict__ resid,
               float* __restrict__ C, int M, int N, int K) {
  __shared__ __align__(16) ushort Al[3][128 * 64];
  __shared__ __align__(16) ushort Bl[3][NFRAG * 64 * 64];
  const int tid = threadIdx.x;
  const int wave = tid >> 6, lane = tid & 63;

  // bijective XCD swizzle (m204), group consecutive blocks by B-panel (bn)
  int nwg = gridDim.x;
  int orig = blockIdx.x;
  int q = nwg >> 3, r8 = nwg & 7, xcd = orig & 7, seq = orig >> 3;
  int swz = (xcd < r8 ? xcd * (q + 1) : r8 * (q + 1) + (xcd - r8) * q) + seq;
  int nm = M >> 7;
  int bm = swz % nm, bn = swz / nm;
  const int row0 = bm * 128, col0 = bn * (64 * NFRAG);

  const int wrow = (wave >> 2) * 64;
  const int wcol = (wave & 3) * (16 * NFRAG);
  const int gchunk = (lane & 7) ^ (lane >> 3);  // pre-swizzled global 16B chunk
  const int NT = K >> 6;

  f32x4 acc[4][NFRAG] = {};

  auto stage = [&](int t) {
    int b = t % 3;
    int k0 = t << 6;
#pragma unroll
    for (int p = 0; p < 2; ++p) {
      int rowb = p * 64 + wave * 8;
      gload_lds16(A + (size_t)(row0 + rowb + (lane >> 3)) * K + k0 + gchunk * 8,
                  &Al[b][rowb * 64]);
    }
#pragma unroll
    for (int p = 0; p < NFRAG; ++p) {
      int rowb = p * 64 + wave * 8;
      gload_lds16(B + (size_t)(col0 + rowb + (lane >> 3)) * K + k0 + gchunk * 8,
                  &Bl[b][rowb * 64]);
    }
  };

  // prologue: fill pipeline 2 tiles deep; wait for tile 0 (its 2+NFRAG loads are oldest)
  stage(0);
  stage(1);
  if constexpr (NFRAG == 4) asm volatile("s_waitcnt vmcnt(6)" ::: "memory");
  else                      asm volatile("s_waitcnt vmcnt(5)" ::: "memory");
  __builtin_amdgcn_s_barrier();

  for (int t = 0; t < NT; ++t) {
    int b = t % 3;
#pragma unroll
    for (int ks = 0; ks < 2; ++ks) {
      bf16x8 af[4], bfr[NFRAG];
      const int koff = (ks * 32 + ((lane >> 4) << 3)) * 2;
#pragma unroll
      for (int mt = 0; mt < 4; ++mt) {
        int rr = wrow + mt * 16 + (lane & 15);
        int off = (rr * 128 + koff) ^ ((rr & 7) << 4);
        af[mt] = *(const bf16x8*)((const char*)&Al[b][0] + off);
      }
#pragma unroll
      for (int nt = 0; nt < NFRAG; ++nt) {
        int rr = wcol + nt * 16 + (lane & 15);
        int off = (rr * 128 + koff) ^ ((rr & 7) << 4);
        bfr[nt] = *(const bf16x8*)((const char*)&Bl[b][0] + off);
      }
      if (ks == 0 && t + 2 < NT) stage(t + 2);
      __builtin_amdgcn_s_barrier();
      asm volatile("s_waitcnt lgkmcnt(0)" ::: "memory");
      __builtin_amdgcn_sched_barrier(0);
      __builtin_amdgcn_s_setprio(1);
#pragma unroll
      for (int nt = 0; nt < NFRAG; ++nt)
#pragma unroll
        for (int mt = 0; mt < 4; ++mt)
          acc[mt][nt] = __builtin_amdgcn_mfma_f32_16x16x32_bf16(af[mt], bfr[nt], acc[mt][nt], 0, 0, 0);
      __builtin_amdgcn_s_setprio(0);
      if (ks == 1) {
        if (t + 2 < NT) {
          // next tile's loads must land; keep t+2's (2+NFRAG) loads in flight
          if constexpr (NFRAG == 4) asm volatile("s_waitcnt vmcnt(6)" ::: "memory");
          else                      asm volatile("s_waitcnt vmcnt(5)" ::: "memory");
        } else {
          asm volatile("s_waitcnt vmcnt(0)" ::: "memory");
        }
      }
      __builtin_amdgcn_s_barrier();
    }
  }

  // epilogue: C/D layout col=lane&15, row=(lane>>4)*4+r (m89-verified); exact tiling, no masks
#pragma unroll
  for (int mt = 0; mt < 4; ++mt) {
#pragma unroll
    for (int nt = 0; nt < NFRAG; ++nt) {
#pragma unroll
      for (int rr = 0; rr < 4; ++rr) {
        int row = row0 + wrow + mt * 16 + ((lane >> 4) << 2) + rr;
        int col = col0 + wcol + nt * 16 + (lane & 15);
        float v = acc[mt][nt][rr] + bias[col];
        if (EPI == 1) v += resid[(size_t)row * N + col];
        C[(size_t)row * N + col] = v;
      }
    }
  }
}

// ---------------- RoPE + split + bf16 cast ----------------
__global__ __launch_bounds__(256)
void rope_split(const float* __restrict__ qkv, ushort* __restrict__ qb,
                ushort* __restrict__ kb, ushort* __restrict__ vb) {
  int tok = blockIdx.x;
  int tid = threadIdx.x;
  __shared__ float cs[32], sn[32];
  if (tid < 32) {
    float d = (float)tid;
    float freq = powf(150000.0f, d / 32.0f);
    float conc = 0.1f * logf(32.0f) + 1.0f;
    float lg = logf(150000.0f);
    float low = 32.0f * logf(4096.0f / (32.0f * 6.2831853f)) / lg;
    float high = 32.0f * logf(4096.0f / 6.2831853f) / lg;
    float ramp = (d - low) / (high - low);
    float cl = fminf(fmaxf(ramp, 0.0f), 1.0f);
    float mask = 1.0f - cl;
    float inv_freq = (1.0f - mask) / (32.0f * freq) + mask / freq;
    float fr = (float)tok * inv_freq;
    cs[tid] = cosf(fr) * conc;
    sn[tid] = sinf(fr) * conc;
  }
  __syncthreads();
  const float* row = qkv + (size_t)tok * QKV_DIM;
#pragma unroll
  for (int it = 0; it < 8; ++it) {
    int p = tid + it * 256;
    int hd = p >> 5, d = p & 31;
    float x1 = row[hd * 64 + d], x2 = row[hd * 64 + d + 32];
    float c = cs[d], s = sn[d];
    size_t o = ((size_t)tok * NH + hd) * HD + d;
    qb[o] = f2bf(x1 * c - x2 * s);
    qb[o + 32] = f2bf(x2 * c + x1 * s);
  }
  {
    int p = tid;
    int hd = p >> 5, d = p & 31;
    float x1 = row[4096 + hd * 64 + d], x2 = row[4096 + hd * 64 + d + 32];
    float c = cs[d], s = sn[d];
    size_t o = ((size_t)tok * NKV + hd) * HD + d;
    kb[o] = f2bf(x1 * c - x2 * s);
    kb[o + 32] = f2bf(x2 * c + x1 * s);
  }
#pragma unroll
  for (int it = 0; it < 2; ++it) {
    int p = tid + it * 256;
    vb[(size_t)tok * (NKV * HD) + p] = f2bf(row[4608 + p]);
  }
}

// ---------------- attention: sliding window 128 + sink ----------------
__global__ __launch_bounds__(512)
void attn_fused(const ushort* __restrict__ qb, const ushort* __restrict__ kb,
                const ushort* __restrict__ vb, const float* __restrict__ sinks,
                ushort* __restrict__ attn, int n) {
  __shared__ __align__(16) ushort Kl[160 * 64];
  __shared__ __align__(16) ushort Vt[64 * 168];
  __shared__ __align__(16) ushort Pl[8][32 * 40];
  int tid = threadIdx.x;
  int wave = tid >> 6, lane = tid & 63;
  int qstart = blockIdx.x * 32;
  int kv = blockIdx.y;
  int head = kv * 8 + wave;
  int key0 = qstart - 128;

  for (int i = 0; i < 3; ++i) {
    int rowb = i * 64 + wave * 8;
    if (rowb < 160) {
      int r = rowb + (lane >> 3);
      int gj = key0 + r; if (gj < 0) gj = 0;
      int chunk = (lane & 7) ^ (lane >> 3);
      gload_lds16(kb + ((size_t)gj * NKV + kv) * HD + chunk * 8, Kl + rowb * 64);
    }
  }
  for (int e = tid; e < 160 * 16; e += 512) {
    int j = e >> 4, d4 = (e & 15) << 2;
    int gj = key0 + j; if (gj < 0) gj = 0;
    ushort4 v = *(const ushort4*)(vb + ((size_t)gj * NKV + kv) * HD + d4);
    Vt[(d4 + 0) * 168 + j] = v.x;
    Vt[(d4 + 1) * 168 + j] = v.y;
    Vt[(d4 + 2) * 168 + j] = v.z;
    Vt[(d4 + 3) * 168 + j] = v.w;
  }
  bf16x8 qf[2][2];
#pragma unroll
  for (int mt = 0; mt < 2; ++mt)
#pragma unroll
    for (int ks = 0; ks < 2; ++ks) {
      int r = qstart + mt * 16 + (lane & 15);
      int kk = ks * 32 + ((lane >> 4) << 3);
      qf[mt][ks] = *(const bf16x8*)(qb + ((size_t)r * NH + head) * HD + kk);
    }
  __syncthreads();

  f32x4 s[2][10] = {};
#pragma unroll
  for (int nt = 0; nt < 10; ++nt) {
#pragma unroll
    for (int ks = 0; ks < 2; ++ks) {
      int r = nt * 16 + (lane & 15);
      int off = (r * 128 + (ks * 32 + ((lane >> 4) << 3)) * 2) ^ ((r & 7) << 4);
      bf16x8 kf = *(const bf16x8*)((const char*)Kl + off);
      s[0][nt] = __builtin_amdgcn_mfma_f32_16x16x32_bf16(qf[0][ks], kf, s[0][nt], 0, 0, 0);
      s[1][nt] = __builtin_amdgcn_mfma_f32_16x16x32_bf16(qf[1][ks], kf, s[1][nt], 0, 0, 0);
    }
  }

  float lrow[2][4];
  float snk = sinks[head];
#pragma unroll
  for (int mt = 0; mt < 2; ++mt) {
#pragma unroll
    for (int r = 0; r < 4; ++r) {
      int i = qstart + mt * 16 + ((lane >> 4) << 2) + r;
      float mx = -1e30f;
#pragma unroll
      for (int nt = 0; nt < 10; ++nt) {
        int j = key0 + nt * 16 + (lane & 15);
        bool ok = (j >= 0) && (j <= i) && (j > i - WINDOW);
        float val = ok ? s[mt][nt][r] * SM_SCALE : -1e30f;
        s[mt][nt][r] = val;
        mx = fmaxf(mx, val);
      }
      mx = fmaxf(mx, __shfl_xor(mx, 1, 64));
      mx = fmaxf(mx, __shfl_xor(mx, 2, 64));
      mx = fmaxf(mx, __shfl_xor(mx, 4, 64));
      mx = fmaxf(mx, __shfl_xor(mx, 8, 64));
      mx = fmaxf(mx, snk);
      float sum = 0.f;
#pragma unroll
      for (int nt = 0; nt < 10; ++nt) {
        float p = expf(s[mt][nt][r] - mx);
        s[mt][nt][r] = p;
        sum += p;
      }
      sum += __shfl_xor(sum, 1, 64);
      sum += __shfl_xor(sum, 2, 64);
      sum += __shfl_xor(sum, 4, 64);
      sum += __shfl_xor(sum, 8, 64);
      sum += expf(snk - mx);
      lrow[mt][r] = sum;
    }
  }

  f32x4 o[2][4] = {};
#pragma unroll
  for (int kc = 0; kc < 5; ++kc) {
    __syncthreads();
#pragma unroll
    for (int mt = 0; mt < 2; ++mt)
#pragma unroll
      for (int t2 = 0; t2 < 2; ++t2) {
        int nt = kc * 2 + t2;
#pragma unroll
        for (int r = 0; r < 4; ++r) {
          int prow = mt * 16 + ((lane >> 4) << 2) + r;
          int pcol = t2 * 16 + (lane & 15);
          Pl[wave][prow * 40 + pcol] = f2bf(s[mt][nt][r]);
        }
      }
    __syncthreads();
    bf16x8 pa[2];
#pragma unroll
    for (int mt = 0; mt < 2; ++mt) {
      int r = mt * 16 + (lane & 15);
      pa[mt] = *(const bf16x8*)(&Pl[wave][r * 40 + ((lane >> 4) << 3)]);
    }
#pragma unroll
    for (int nt = 0; nt < 4; ++nt) {
      int d = nt * 16 + (lane & 15);
      int kk = kc * 32 + ((lane >> 4) << 3);
      bf16x8 vf = *(const bf16x8*)(&Vt[d * 168 + kk]);
      o[0][nt] = __builtin_amdgcn_mfma_f32_16x16x32_bf16(pa[0], vf, o[0][nt], 0, 0, 0);
      o[1][nt] = __builtin_amdgcn_mfma_f32_16x16x32_bf16(pa[1], vf, o[1][nt], 0, 0, 0);
    }
  }

#pragma unroll
  for (int mt = 0; mt < 2; ++mt)
#pragma unroll
    for (int nt = 0; nt < 4; ++nt)
#pragma unroll
      for (int r = 0; r < 4; ++r) {
        int row = qstart + mt * 16 + ((lane >> 4) << 2) + r;
        int d = nt * 16 + (lane & 15);
        float val = o[mt][nt][r] / lrow[mt][r];
        attn[((size_t)row * NH + head) * HD + d] = f2bf(val);
      }
}

extern "C" void kernel_launch(void* const* d_in, const int* in_sizes, int n_in,
                              void* d_out, int out_size, void* d_ws, size_t ws_size,
                              hipStream_t stream) {
  const float* x      = (const float*)d_in[0];
  const float* nscale = (const float*)d_in[1];
  const float* qkv_w  = (const float*)d_in[2];
  const float* qkv_b  = (const float*)d_in[3];
  const float* out_w  = (const float*)d_in[4];
  const float* out_b  = (const float*)d_in[5];
  const float* sinks  = (const float*)d_in[6];
  float* out = (float*)d_out;
  int n = in_sizes[0] / HIDDEN;  // 1536

  char* ws = (char*)d_ws;
  size_t off = 0;
  auto alloc = [&](size_t bytes) {
    char* p = ws + off;
    off += (bytes + 255) & ~(size_t)255;
    return p;
  };
  ushort* t_bf    = (ushort*)alloc((size_t)n * HIDDEN * 2);
  ushort* qkvw_bf = (ushort*)alloc((size_t)QKV_DIM * HIDDEN * 2);
  ushort* outw_bf = (ushort*)alloc((size_t)HIDDEN * ATT_DIM * 2);
  float*  qkv     = (float*)alloc((size_t)n * QKV_DIM * 4);
  ushort* q_bf    = (ushort*)alloc((size_t)n * NH * HD * 2);
  ushort* k_bf    = (ushort*)alloc((size_t)n * NKV * HD * 2);
  ushort* v_bf    = (ushort*)alloc((size_t)n * NKV * HD * 2);
  ushort* attn    = (ushort*)alloc((size_t)n * ATT_DIM * 2);

  cvt_f32_bf16<<<2048, 256, 0, stream>>>(qkv_w, qkvw_bf, QKV_DIM * HIDDEN / 4);
  cvt_f32_bf16<<<2048, 256, 0, stream>>>(out_w, outw_bf, HIDDEN * ATT_DIM / 4);
  rmsnorm_bf16<<<n, 256, 0, stream>>>(x, nscale, t_bf);
  // QKV: M=1536 N=5120 K=2880, BN=256 -> 12x20=240 wg
  gemm_pipe<4, 0><<<(n / 128) * (QKV_DIM / 256), 512, 0, stream>>>(
      t_bf, qkvw_bf, qkv_b, nullptr, qkv, n, QKV_DIM, HIDDEN);
  rope_split<<<n, 256, 0, stream>>>(qkv, q_bf, k_bf, v_bf);
  attn_fused<<<dim3(n / 32, NKV), 512, 0, stream>>>(q_bf, k_bf, v_bf, sinks, attn, n);
  // out: M=1536 N=2880 K=4096, BN=192 -> 12x15=180 wg
  gemm_pipe<3, 1><<<(n / 128) * (HIDDEN / 192), 512, 0, stream>>>(
      attn, outw_bf, out_b, x, out, n, HIDDEN, ATT_DIM);
}